// Round 7
// baseline (714.790 us; speedup 1.0000x reference)
//
#include <hip/hip_runtime.h>
#include <math.h>

#define TT 512
#define BB 512
#define CC 32
#define CIN 33
#define HH 128
#define EPSF 1e-12f
#define CH 16              // timesteps per x-chunk staged in LDS
#define NCH (TT / CH)
#define RB 2               // batch rows per block

typedef _Float16 half8 __attribute__((ext_vector_type(8)));
typedef _Float16 half4v __attribute__((ext_vector_type(4)));
typedef _Float16 half2v __attribute__((ext_vector_type(2)));
typedef float f32x4 __attribute__((ext_vector_type(4)));

#define MFMA16H(a, b, c) __builtin_amdgcn_mfma_f32_16x16x32_f16(a, b, c, 0, 0, 0)

__device__ __forceinline__ float fsig(float x) {
    return __builtin_amdgcn_rcpf(1.f + __expf(-x));
}
__device__ __forceinline__ float ftanh(float x) {
    return 1.f - 2.f * __builtin_amdgcn_rcpf(1.f + __expf(2.f * x));
}

// ---------------------------------------------------------------------------
// Kernel 1: s[t] = mean_c std_b(x[:,t,c], ddof=1)   -> ws[0..511]
// ---------------------------------------------------------------------------
__global__ void std_kernel(const float* __restrict__ x, float* __restrict__ ws) {
    const int t = blockIdx.x;
    const int c = threadIdx.x & 31;
    const int sl = threadIdx.x >> 5;
    float sum = 0.f, sq = 0.f;
    for (int k = 0; k < 64; ++k) {
        const int b = sl * 64 + k;
        float v = x[((size_t)b * TT + t) * CC + c];
        sum += v;
        sq  = fmaf(v, v, sq);
    }
    __shared__ float rs[8][32];
    __shared__ float rq[8][32];
    rs[sl][c] = sum; rq[sl][c] = sq;
    __syncthreads();
    if (threadIdx.x < 32) {
        float S = 0.f, Q = 0.f;
        for (int i = 0; i < 8; ++i) { S += rs[i][threadIdx.x]; Q += rq[i][threadIdx.x]; }
        float mean = S / 512.0f;
        float var  = (Q - 512.0f * mean * mean) / 511.0f;
        rs[0][threadIdx.x] = sqrtf(fmaxf(var, 0.f));
    }
    __syncthreads();
    if (threadIdx.x == 0) {
        float m = 0.f;
        for (int i = 0; i < 32; ++i) m += rs[0][i];
        ws[t] = m / 32.0f;
    }
}

// ---------------------------------------------------------------------------
// Kernel 2: sigmas -> ws[512]=sig_ih, ws[513]=sig_hh, ws[514]=sig_fc
// ---------------------------------------------------------------------------
__global__ void sigma_kernel(const float* __restrict__ w_ih, const float* __restrict__ u_ih,
                             const float* __restrict__ w_hh, const float* __restrict__ u_hh,
                             const float* __restrict__ fc_w, const float* __restrict__ u_fc,
                             float* __restrict__ ws) {
    const int tid = threadIdx.x;
    __shared__ float red[512];
    __shared__ float vv[128];

    {   // sigma_hh
        const int c = tid & 127, q = tid >> 7;
        float part = 0.f;
        for (int g = q * 128; g < q * 128 + 128; ++g)
            part = fmaf(w_hh[g * HH + c], u_hh[g], part);
        red[tid] = part;
        __syncthreads();
        if (tid < 128) vv[tid] = red[tid] + red[tid + 128] + red[tid + 256] + red[tid + 384];
        __syncthreads();
        red[tid] = (tid < 128) ? vv[tid] * vv[tid] : 0.f;
        __syncthreads();
        for (int s = 64; s >= 1; s >>= 1) { if (tid < s) red[tid] += red[tid + s]; __syncthreads(); }
        const float nv = sqrtf(red[0]);
        __syncthreads();
        if (tid < 128) vv[tid] = vv[tid] / (nv + EPSF);
        __syncthreads();
        float wv = 0.f;
        for (int c2 = 0; c2 < 128; ++c2) wv = fmaf(w_hh[tid * HH + c2], vv[c2], wv);
        red[tid] = wv * wv;
        __syncthreads();
        for (int s = 256; s >= 1; s >>= 1) { if (tid < s) red[tid] += red[tid + s]; __syncthreads(); }
        if (tid == 0) { float ns2 = red[0]; ws[513] = ns2 / (sqrtf(ns2) + EPSF); }
        __syncthreads();
    }
    {   // sigma_ih
        float part = 0.f;
        if (tid < CIN) {
            for (int g = 0; g < 512; ++g) part = fmaf(w_ih[g * CIN + tid], u_ih[g], part);
            red[tid] = part;
        }
        __syncthreads();
        if (tid == 0) {
            float n2 = 0.f;
            for (int i = 0; i < CIN; ++i) n2 += red[i] * red[i];
            red[400] = sqrtf(n2);
        }
        __syncthreads();
        const float nv = red[400];
        if (tid < CIN) vv[tid] = red[tid] / (nv + EPSF);
        __syncthreads();
        float wv = 0.f;
        for (int c2 = 0; c2 < CIN; ++c2) wv = fmaf(w_ih[tid * CIN + c2], vv[c2], wv);
        red[tid] = wv * wv;
        __syncthreads();
        for (int s = 256; s >= 1; s >>= 1) { if (tid < s) red[tid] += red[tid + s]; __syncthreads(); }
        if (tid == 0) { float ns2 = red[0]; ws[512] = ns2 / (sqrtf(ns2) + EPSF); }
        __syncthreads();
    }
    {   // sigma_fc
        red[tid] = (tid < 128) ? fc_w[tid] * fc_w[tid] : 0.f;
        __syncthreads();
        for (int s = 64; s >= 1; s >>= 1) { if (tid < s) red[tid] += red[tid + s]; __syncthreads(); }
        if (tid == 0) {
            float nw2 = red[0];
            float u0  = u_fc[0];
            float nv  = fabsf(u0) * sqrtf(nw2);
            float wv  = u0 * nw2 / (nv + EPSF);
            ws[514]   = wv * wv / (fabsf(wv) + EPSF);
        }
    }
}

// ---------------------------------------------------------------------------
// Kernel 3: fp16 MFMA LSTM. 256 blocks x 2 batch rows, 256 threads (4 waves).
// Round-7: all 256 CUs active (was 128); per-CU LDS traffic ~halved (4 waves
// re-read the broadcast h instead of 8). Wave w owns 8 N-tiles (2 col-sets x
// 4 gates) = 160 weight VGPRs, waves_per_eu(1,1) for the 512-reg budget.
// A-frag rows 2..15 are zeros via exec-masked loads (no big zero arrays).
// ---------------------------------------------------------------------------
__global__ __attribute__((amdgpu_flat_work_group_size(256, 256), amdgpu_waves_per_eu(1, 1)))
void lstm_mfma(
    const float* __restrict__ x,
    const float* __restrict__ w_ih, const float* __restrict__ w_hh,
    const float* __restrict__ b_ih, const float* __restrict__ b_hh,
    const float* __restrict__ attn_w, const float* __restrict__ attn_b,
    const float* __restrict__ fc_w, const float* __restrict__ fc_b,
    const float* __restrict__ ws,
    float* __restrict__ out)
{
    const int tid = threadIdx.x;
    const int w   = tid >> 6;          // wave 0..3
    const int l   = tid & 63;          // lane
    const int m   = l & 15;            // A-row / B-col index
    const int q   = l >> 4;            // quad 0..3
    const int b0  = blockIdx.x * RB;

    // activation-element ownership: row r, colset cs_l, col jcol
    const int r    = q & 1;
    const int cs_l = q >> 1;
    const int jcol = 16 * w + 64 * cs_l + m;

    const float rih = 1.f / ws[512];
    const float rhh = 1.f / ws[513];
    const float rfc = 1.f / ws[514];
    const float attb = attn_b[0];

    __shared__ __align__(16) _Float16 hs[2][RB][136];        // h planes, 2 real rows
    __shared__ __align__(16) _Float16 xs[2][CH][RB][48];     // x chunks
    __shared__ float ss[2][CH];
    __shared__ __align__(8) float gact[4][4][2][16][2];      // [wave][gate][cs][col][row]
    __shared__ float bcast[2][RB];
    __shared__ float Sf[RB];
    __shared__ float sc[RB][132];

    // ---- stationary fp16 weights: Bf[p][cs][kt] ----
    half8 Bf[4][2][5];
    float biasg[4][2], w32g[4][2];
#pragma unroll
    for (int p = 0; p < 4; ++p) {
#pragma unroll
        for (int cs = 0; cs < 2; ++cs) {
            const int g = 128 * p + 16 * (w + 4 * cs) + m;
#pragma unroll
            for (int kt = 0; kt < 4; ++kt) {
                const float* src = w_hh + (size_t)g * HH + kt * 32 + q * 8;
#pragma unroll
                for (int i = 0; i < 8; ++i) Bf[p][cs][kt][i] = (_Float16)(src[i] * rhh);
            }
            {
                const float* src = w_ih + (size_t)g * CIN + q * 8;
#pragma unroll
                for (int i = 0; i < 8; ++i) Bf[p][cs][4][i] = (_Float16)(src[i] * rih);
            }
            w32g[p][cs]  = w_ih[(size_t)g * CIN + 32] * rih;
            biasg[p][cs] = b_ih[g] + b_hh[g];
        }
    }
#pragma unroll
    for (int p = 0; p < 4; ++p)
#pragma unroll
        for (int cs = 0; cs < 2; ++cs) {
#pragma unroll
            for (int kt = 0; kt < 5; ++kt) asm volatile("" : "+v"(Bf[p][cs][kt]));
            asm volatile("" : "+v"(biasg[p][cs]), "+v"(w32g[p][cs]));
        }
    const float fcwj = fc_w[jcol] * rfc;

    // logit-phase constants (waves 0..1 handle batch rows 0..1, lane = 2 cols)
    const float aw0 = attn_w[2 * l];
    const float aw1 = attn_w[2 * l + 1];

    // zero h_{-1} planes (both buffers)
    for (int i = tid; i < 2 * RB * 136; i += 256) (&hs[0][0][0])[i] = (_Float16)0.f;
    // stage chunk 0 + ss[0]
    {
        const int c4 = tid & 7, rr = (tid >> 3) & 1, k = tid >> 4;
        float4 xv = *reinterpret_cast<const float4*>(x + ((size_t)(b0 + rr) * TT + k) * CC + c4 * 4);
        half4v hv = {(_Float16)xv.x, (_Float16)xv.y, (_Float16)xv.z, (_Float16)xv.w};
        *(half4v*)&xs[0][k][rr][c4 * 4] = hv;
    }
    if (tid < CH) ss[0][tid] = ws[tid];

    float c_st = 0.f, P = 0.f, hprev = 0.f, hpp = 0.f;
    float Sreg = 0.f;
    __syncthreads();

    for (int tc = 0; tc < NCH; ++tc) {
        const int cb = tc & 1;

        // stage next chunk
        if (tc + 1 < NCH) {
            const int nb  = (tc + 1) & 1;
            const int t0n = (tc + 1) * CH;
            const int c4 = tid & 7, rr = (tid >> 3) & 1, k = tid >> 4;
            float4 xv = *reinterpret_cast<const float4*>(
                x + ((size_t)(b0 + rr) * TT + (t0n + k)) * CC + c4 * 4);
            half4v hv = {(_Float16)xv.x, (_Float16)xv.y, (_Float16)xv.z, (_Float16)xv.w};
            *(half4v*)&xs[nb][k][rr][c4 * 4] = hv;
            if (tid < CH) ss[nb][tid] = ws[t0n + tid];
        }

        for (int k = 0; k < CH; ++k) {
            const int t  = tc * CH + k;
            const int hb = (t + 1) & 1;    // buffer holding h_{t-1}

            // ---- A-frags: rows >= RB are zero (exec-masked loads) ----
            half8 ah0 = (half8)(_Float16)0.f, ah1 = ah0, ah2 = ah0, ah3 = ah0, ah4 = ah0;
            if (m < RB) {
                ah0 = *(const half8*)&hs[hb][m][0 * 32 + q * 8];
                ah1 = *(const half8*)&hs[hb][m][1 * 32 + q * 8];
                ah2 = *(const half8*)&hs[hb][m][2 * 32 + q * 8];
                ah3 = *(const half8*)&hs[hb][m][3 * 32 + q * 8];
                ah4 = *(const half8*)&xs[cb][k][m][q * 8];
            }
            const float s_t = ss[cb][k];

            // ---- logit for h_{t-1}: wave rr<RB handles row rr ----
            if (t > 0 && w < RB) {
                half2v hh = *(const half2v*)&hs[hb][w][2 * l];
                float acc = fmaf(aw0, (float)hh[0], aw1 * (float)hh[1]);
#pragma unroll
                for (int off = 1; off < 64; off <<= 1) acc += __shfl_xor(acc, off, 64);
                float beta = __expf(acc + attb);
                Sreg += beta;
                if (l == 0) bcast[t & 1][w] = beta;
            }

            // ---- P update for h_{t-2} ----
            if (t >= 2) P = fmaf(bcast[(t - 1) & 1][r], hpp, P);

            // ---- gates: C init + 40 MFMA ----
            f32x4 acc[4][2];
#pragma unroll
            for (int p = 0; p < 4; ++p)
#pragma unroll
                for (int cs = 0; cs < 2; ++cs) {
                    float c0 = fmaf(w32g[p][cs], s_t, biasg[p][cs]);
                    acc[p][cs] = (f32x4){c0, c0, c0, c0};
                }
#pragma unroll
            for (int p = 0; p < 4; ++p)
#pragma unroll
                for (int cs = 0; cs < 2; ++cs) {
                    acc[p][cs] = MFMA16H(ah0, Bf[p][cs][0], acc[p][cs]);
                    acc[p][cs] = MFMA16H(ah1, Bf[p][cs][1], acc[p][cs]);
                    acc[p][cs] = MFMA16H(ah2, Bf[p][cs][2], acc[p][cs]);
                    acc[p][cs] = MFMA16H(ah3, Bf[p][cs][3], acc[p][cs]);
                    acc[p][cs] = MFMA16H(ah4, Bf[p][cs][4], acc[p][cs]);
                }

            // ---- gate compaction: q=0 lanes hold rows 0..1; spread 1/lane ----
            if (q == 0) {
#pragma unroll
                for (int p = 0; p < 4; ++p)
#pragma unroll
                    for (int cs = 0; cs < 2; ++cs) {
                        float2 v2 = make_float2(acc[p][cs][0], acc[p][cs][1]);
                        *(float2*)&gact[w][p][cs][m][0] = v2;
                    }
            }
            float g0 = gact[w][0][cs_l][m][r];
            float g1 = gact[w][1][cs_l][m][r];
            float g2 = gact[w][2][cs_l][m][r];
            float g3 = gact[w][3][cs_l][m][r];

            // ---- activation + state update: ONE element per lane ----
            {
                float ig = fsig(g0);
                float fg = fsig(g1);
                float gg = ftanh(g2);
                float og = fsig(g3);
                c_st = fmaf(fg, c_st, ig * gg);
                float hv = og * ftanh(c_st);
                hpp   = hprev;
                hprev = hv;
                hs[t & 1][r][jcol] = (_Float16)hv;
            }

            __syncthreads();   // single barrier per step
        }
    }

    // ---- epilogue ----
    P = fmaf(bcast[1][r], hpp, P);            // beta_510 * h_510
    if (w < RB) {                              // beta_511 from hs[1]
        half2v hh = *(const half2v*)&hs[1][w][2 * l];
        float acc = fmaf(aw0, (float)hh[0], aw1 * (float)hh[1]);
#pragma unroll
        for (int off = 1; off < 64; off <<= 1) acc += __shfl_xor(acc, off, 64);
        float beta = __expf(acc + attb);
        Sreg += beta;
        if (l == 0) { bcast[0][w] = beta; Sf[w] = Sreg; }
    }
    __syncthreads();
    {
        float Pv = fmaf(bcast[0][r], hprev, P);
        sc[r][jcol] = Pv * __builtin_amdgcn_rcpf(Sf[r]) * fcwj;
    }
    __syncthreads();
    if (w < RB) {
        float2 vv = *(const float2*)&sc[w][2 * l];
        float a = vv.x + vv.y;
#pragma unroll
        for (int off = 1; off < 64; off <<= 1) a += __shfl_xor(a, off, 64);
        if (l == 0) out[b0 + w] = a + fc_b[0];
    }
}

// ---------------------------------------------------------------------------
extern "C" void kernel_launch(void* const* d_in, const int* in_sizes, int n_in,
                              void* d_out, int out_size, void* d_ws, size_t ws_size,
                              hipStream_t stream) {
    const float* x      = (const float*)d_in[0];
    const float* w_ih   = (const float*)d_in[1];
    const float* u_ih   = (const float*)d_in[2];
    const float* w_hh   = (const float*)d_in[3];
    const float* u_hh   = (const float*)d_in[4];
    const float* b_ih   = (const float*)d_in[5];
    const float* b_hh   = (const float*)d_in[6];
    const float* attn_w = (const float*)d_in[7];
    const float* attn_b = (const float*)d_in[8];
    const float* fc_w   = (const float*)d_in[9];
    const float* u_fc   = (const float*)d_in[10];
    const float* fc_b   = (const float*)d_in[11];
    float* ws  = (float*)d_ws;
    float* out = (float*)d_out;

    std_kernel<<<TT, 256, 0, stream>>>(x, ws);
    sigma_kernel<<<1, 512, 0, stream>>>(w_ih, u_ih, w_hh, u_hh, fc_w, u_fc, ws);
    lstm_mfma<<<BB / RB, 256, 0, stream>>>(x, w_ih, w_hh, b_ih, b_hh,
                                           attn_w, attn_b, fc_w, fc_b, ws, out);
}

// Round 9
// 593.949 us; speedup vs baseline: 1.2035x; 1.2035x over previous
//
#include <hip/hip_runtime.h>
#include <math.h>

#define TT 512
#define BB 512
#define CC 32
#define CIN 33
#define HH 128
#define EPSF 1e-12f
#define CH 16              // timesteps per x-chunk staged in LDS
#define NCH (TT / CH)
#define RB 2               // batch rows per block

typedef _Float16 half8 __attribute__((ext_vector_type(8)));
typedef _Float16 half4v __attribute__((ext_vector_type(4)));
typedef _Float16 half2v __attribute__((ext_vector_type(2)));
typedef float f32x4 __attribute__((ext_vector_type(4)));

#define MFMA16H(a, b, c) __builtin_amdgcn_mfma_f32_16x16x32_f16(a, b, c, 0, 0, 0)

__device__ __forceinline__ float fsig(float x) {
    return __builtin_amdgcn_rcpf(1.f + __expf(-x));
}
__device__ __forceinline__ float ftanh(float x) {
    return 1.f - 2.f * __builtin_amdgcn_rcpf(1.f + __expf(2.f * x));
}
// full-wave (64) sum via DPP; result valid on lane 63 ONLY. VALU pipe, no LDS.
__device__ __forceinline__ float wave_sum_dpp(float x) {
    x += __int_as_float(__builtin_amdgcn_update_dpp(0, __float_as_int(x), 0x111, 0xf, 0xf, true));
    x += __int_as_float(__builtin_amdgcn_update_dpp(0, __float_as_int(x), 0x112, 0xf, 0xf, true));
    x += __int_as_float(__builtin_amdgcn_update_dpp(0, __float_as_int(x), 0x114, 0xf, 0xf, true));
    x += __int_as_float(__builtin_amdgcn_update_dpp(0, __float_as_int(x), 0x118, 0xf, 0xf, true));
    x += __int_as_float(__builtin_amdgcn_update_dpp(0, __float_as_int(x), 0x142, 0xa, 0xf, true));
    x += __int_as_float(__builtin_amdgcn_update_dpp(0, __float_as_int(x), 0x143, 0xc, 0xf, true));
    return x;
}
// sum of lanes 0..15 (row 0) via DPP; result valid on lane 15.
__device__ __forceinline__ float row_sum_dpp(float x) {
    x += __int_as_float(__builtin_amdgcn_update_dpp(0, __float_as_int(x), 0x111, 0xf, 0xf, true));
    x += __int_as_float(__builtin_amdgcn_update_dpp(0, __float_as_int(x), 0x112, 0xf, 0xf, true));
    x += __int_as_float(__builtin_amdgcn_update_dpp(0, __float_as_int(x), 0x114, 0xf, 0xf, true));
    x += __int_as_float(__builtin_amdgcn_update_dpp(0, __float_as_int(x), 0x118, 0xf, 0xf, true));
    return x;
}

// ---------------------------------------------------------------------------
// Kernel 1: s[t] = mean_c std_b(x[:,t,c], ddof=1)   -> ws[0..511]
// ---------------------------------------------------------------------------
__global__ void std_kernel(const float* __restrict__ x, float* __restrict__ ws) {
    const int t = blockIdx.x;
    const int c = threadIdx.x & 31;
    const int sl = threadIdx.x >> 5;
    float sum = 0.f, sq = 0.f;
    for (int k = 0; k < 64; ++k) {
        const int b = sl * 64 + k;
        float v = x[((size_t)b * TT + t) * CC + c];
        sum += v;
        sq  = fmaf(v, v, sq);
    }
    __shared__ float rs[8][32];
    __shared__ float rq[8][32];
    rs[sl][c] = sum; rq[sl][c] = sq;
    __syncthreads();
    if (threadIdx.x < 32) {
        float S = 0.f, Q = 0.f;
        for (int i = 0; i < 8; ++i) { S += rs[i][threadIdx.x]; Q += rq[i][threadIdx.x]; }
        float mean = S / 512.0f;
        float var  = (Q - 512.0f * mean * mean) / 511.0f;
        rs[0][threadIdx.x] = sqrtf(fmaxf(var, 0.f));
    }
    __syncthreads();
    if (threadIdx.x == 0) {
        float m = 0.f;
        for (int i = 0; i < 32; ++i) m += rs[0][i];
        ws[t] = m / 32.0f;
    }
}

// ---------------------------------------------------------------------------
// Kernel 2: sigmas -> ws[512]=sig_ih, ws[513]=sig_hh, ws[514]=sig_fc
// ---------------------------------------------------------------------------
__global__ void sigma_kernel(const float* __restrict__ w_ih, const float* __restrict__ u_ih,
                             const float* __restrict__ w_hh, const float* __restrict__ u_hh,
                             const float* __restrict__ fc_w, const float* __restrict__ u_fc,
                             float* __restrict__ ws) {
    const int tid = threadIdx.x;
    __shared__ float red[512];
    __shared__ float vv[128];

    {   // sigma_hh
        const int c = tid & 127, q = tid >> 7;
        float part = 0.f;
        for (int g = q * 128; g < q * 128 + 128; ++g)
            part = fmaf(w_hh[g * HH + c], u_hh[g], part);
        red[tid] = part;
        __syncthreads();
        if (tid < 128) vv[tid] = red[tid] + red[tid + 128] + red[tid + 256] + red[tid + 384];
        __syncthreads();
        red[tid] = (tid < 128) ? vv[tid] * vv[tid] : 0.f;
        __syncthreads();
        for (int s = 64; s >= 1; s >>= 1) { if (tid < s) red[tid] += red[tid + s]; __syncthreads(); }
        const float nv = sqrtf(red[0]);
        __syncthreads();
        if (tid < 128) vv[tid] = vv[tid] / (nv + EPSF);
        __syncthreads();
        float wv = 0.f;
        for (int c2 = 0; c2 < 128; ++c2) wv = fmaf(w_hh[tid * HH + c2], vv[c2], wv);
        red[tid] = wv * wv;
        __syncthreads();
        for (int s = 256; s >= 1; s >>= 1) { if (tid < s) red[tid] += red[tid + s]; __syncthreads(); }
        if (tid == 0) { float ns2 = red[0]; ws[513] = ns2 / (sqrtf(ns2) + EPSF); }
        __syncthreads();
    }
    {   // sigma_ih
        float part = 0.f;
        if (tid < CIN) {
            for (int g = 0; g < 512; ++g) part = fmaf(w_ih[g * CIN + tid], u_ih[g], part);
            red[tid] = part;
        }
        __syncthreads();
        if (tid == 0) {
            float n2 = 0.f;
            for (int i = 0; i < CIN; ++i) n2 += red[i] * red[i];
            red[400] = sqrtf(n2);
        }
        __syncthreads();
        const float nv = red[400];
        if (tid < CIN) vv[tid] = red[tid] / (nv + EPSF);
        __syncthreads();
        float wv = 0.f;
        for (int c2 = 0; c2 < CIN; ++c2) wv = fmaf(w_ih[tid * CIN + c2], vv[c2], wv);
        red[tid] = wv * wv;
        __syncthreads();
        for (int s = 256; s >= 1; s >>= 1) { if (tid < s) red[tid] += red[tid + s]; __syncthreads(); }
        if (tid == 0) { float ns2 = red[0]; ws[512] = ns2 / (sqrtf(ns2) + EPSF); }
        __syncthreads();
    }
    {   // sigma_fc
        red[tid] = (tid < 128) ? fc_w[tid] * fc_w[tid] : 0.f;
        __syncthreads();
        for (int s = 64; s >= 1; s >>= 1) { if (tid < s) red[tid] += red[tid + s]; __syncthreads(); }
        if (tid == 0) {
            float nw2 = red[0];
            float u0  = u_fc[0];
            float nv  = fabsf(u0) * sqrtf(nw2);
            float wv  = u0 * nw2 / (nv + EPSF);
            ws[514]   = wv * wv / (fabsf(wv) + EPSF);
        }
    }
}

// ---------------------------------------------------------------------------
// Kernel 3: fp16 MFMA LSTM. 256 blocks x 2 batch rows, 512 threads (8 waves,
// 2/SIMD for overlap -- round-7 showed 1/SIMD exposes the serial chain).
// Wave w owns cols 16w..16w+15 of all 4 gates (R6 mapping, 80 weight regs,
// kt-interleaved MFMA order = 4 independent acc chains). NO gact round-trip:
// with 2 rows, gates live in regs 0,1 of q=0 lanes -> activations there.
// Logit reduction via DPP (VALU) instead of 6 dependent ds_bpermutes.
// ---------------------------------------------------------------------------
__global__ __attribute__((amdgpu_flat_work_group_size(512, 512), amdgpu_waves_per_eu(2, 2)))
void lstm_mfma(
    const float* __restrict__ x,
    const float* __restrict__ w_ih, const float* __restrict__ w_hh,
    const float* __restrict__ b_ih, const float* __restrict__ b_hh,
    const float* __restrict__ attn_w, const float* __restrict__ attn_b,
    const float* __restrict__ fc_w, const float* __restrict__ fc_b,
    const float* __restrict__ ws,
    float* __restrict__ out)
{
    const int tid = threadIdx.x;
    const int w   = tid >> 6;          // wave 0..7
    const int l   = tid & 63;          // lane
    const int m   = l & 15;            // A-row / B-col index
    const int q   = l >> 4;            // quad 0..3
    const int b0  = blockIdx.x * RB;
    const int jcol = 16 * w + m;       // col owned by q=0 lane m (both rows)

    const float rih = 1.f / ws[512];
    const float rhh = 1.f / ws[513];
    const float rfc = 1.f / ws[514];
    const float attb = attn_b[0];

    __shared__ __align__(16) _Float16 hs[2][RB][136];       // h planes
    __shared__ __align__(16) _Float16 xs[2][CH][RB][48];    // x chunks
    __shared__ float ss[2][CH];
    __shared__ __align__(8) float bcast[2][RB];             // beta per row
    __shared__ float Sf[RB];
    __shared__ float part[8][RB];                           // FC partials

    // ---- stationary fp16 weights: Bf[p][kt] (R6 mapping) ----
    half8 Bf[4][5];
    float biasg[4], w32g[4];
#pragma unroll
    for (int p = 0; p < 4; ++p) {
        const int g = 16 * w + 128 * p + m;
#pragma unroll
        for (int kt = 0; kt < 4; ++kt) {
            const float* src = w_hh + (size_t)g * HH + kt * 32 + q * 8;
#pragma unroll
            for (int i = 0; i < 8; ++i) Bf[p][kt][i] = (_Float16)(src[i] * rhh);
        }
        {
            const float* src = w_ih + (size_t)g * CIN + q * 8;
#pragma unroll
            for (int i = 0; i < 8; ++i) Bf[p][4][i] = (_Float16)(src[i] * rih);
        }
        w32g[p]  = w_ih[(size_t)g * CIN + 32] * rih;
        biasg[p] = b_ih[g] + b_hh[g];
    }
#pragma unroll
    for (int p = 0; p < 4; ++p) {
#pragma unroll
        for (int kt = 0; kt < 5; ++kt) asm volatile("" : "+v"(Bf[p][kt]));
        asm volatile("" : "+v"(biasg[p]), "+v"(w32g[p]));
    }
    const float fcwj = fc_w[jcol] * rfc;

    // logit-phase constants (waves 0..1 handle batch rows 0..1, lane = 2 cols)
    const float aw0 = attn_w[2 * l];
    const float aw1 = attn_w[2 * l + 1];

    // zero h_{-1} planes (both buffers)
    for (int i = tid; i < 2 * RB * 136; i += 512) (&hs[0][0][0])[i] = (_Float16)0.f;
    // stage chunk 0 + ss[0]
    if (tid < 256) {
        const int c4 = tid & 7, rr = (tid >> 3) & 1, k = tid >> 4;
        float4 xv = *reinterpret_cast<const float4*>(x + ((size_t)(b0 + rr) * TT + k) * CC + c4 * 4);
        half4v hv = {(_Float16)xv.x, (_Float16)xv.y, (_Float16)xv.z, (_Float16)xv.w};
        *(half4v*)&xs[0][k][rr][c4 * 4] = hv;
    }
    if (tid < CH) ss[0][tid] = ws[tid];

    float c_st[RB] = {0.f, 0.f};
    float P[RB]    = {0.f, 0.f};
    float hprev[RB] = {0.f, 0.f};
    float hpp[RB]   = {0.f, 0.f};
    float Sreg = 0.f;                      // lane 63 of waves 0,1
    __syncthreads();

    for (int tc = 0; tc < NCH; ++tc) {
        const int cb = tc & 1;

        // stage next chunk (drains at some in-chunk barrier, amortized)
        if (tc + 1 < NCH) {
            const int nb  = (tc + 1) & 1;
            const int t0n = (tc + 1) * CH;
            if (tid < 256) {
                const int c4 = tid & 7, rr = (tid >> 3) & 1, k = tid >> 4;
                float4 xv = *reinterpret_cast<const float4*>(
                    x + ((size_t)(b0 + rr) * TT + (t0n + k)) * CC + c4 * 4);
                half4v hv = {(_Float16)xv.x, (_Float16)xv.y, (_Float16)xv.z, (_Float16)xv.w};
                *(half4v*)&xs[nb][k][rr][c4 * 4] = hv;
            }
            if (tid < CH) ss[nb][tid] = ws[t0n + tid];
        }

        for (int k = 0; k < CH; ++k) {
            const int t  = tc * CH + k;
            const int hb = (t + 1) & 1;    // buffer holding h_{t-1}

            // ---- A-frags (rows >= RB zero, exec-masked reads) ----
            half8 ah0 = (half8)(_Float16)0.f, ah1 = ah0, ah2 = ah0, ah3 = ah0, ah4 = ah0;
            if (m < RB) {
                ah0 = *(const half8*)&hs[hb][m][0 * 32 + q * 8];
                ah1 = *(const half8*)&hs[hb][m][1 * 32 + q * 8];
                ah2 = *(const half8*)&hs[hb][m][2 * 32 + q * 8];
                ah3 = *(const half8*)&hs[hb][m][3 * 32 + q * 8];
                ah4 = *(const half8*)&xs[cb][k][m][q * 8];
            }
            const float s_t = ss[cb][k];

            // logit source read issued early (h_{t-1}, buffer hb — not written this step)
            float dotp = 0.f;
            if (t > 0 && w < RB) {
                half2v hh = *(const half2v*)&hs[hb][w][2 * l];
                dotp = fmaf(aw0, (float)hh[0], aw1 * (float)hh[1]);
            }

            // ---- P update for h_{t-2} (beta written at step t-1) ----
            if (t >= 2) {
                float2 bc = *(const float2*)&bcast[(t - 1) & 1][0];
                P[0] = fmaf(bc.x, hpp[0], P[0]);
                P[1] = fmaf(bc.y, hpp[1], P[1]);
            }

            // ---- gates: C init + 20 MFMA, kt-outer (4 interleaved chains) ----
            f32x4 acc0, acc1, acc2, acc3;
            {
                float c0 = fmaf(w32g[0], s_t, biasg[0]);
                float c1 = fmaf(w32g[1], s_t, biasg[1]);
                float c2 = fmaf(w32g[2], s_t, biasg[2]);
                float c3 = fmaf(w32g[3], s_t, biasg[3]);
                acc0 = (f32x4){c0, c0, c0, c0};
                acc1 = (f32x4){c1, c1, c1, c1};
                acc2 = (f32x4){c2, c2, c2, c2};
                acc3 = (f32x4){c3, c3, c3, c3};
            }
            acc0 = MFMA16H(ah0, Bf[0][0], acc0);
            acc1 = MFMA16H(ah0, Bf[1][0], acc1);
            acc2 = MFMA16H(ah0, Bf[2][0], acc2);
            acc3 = MFMA16H(ah0, Bf[3][0], acc3);
            acc0 = MFMA16H(ah1, Bf[0][1], acc0);
            acc1 = MFMA16H(ah1, Bf[1][1], acc1);
            acc2 = MFMA16H(ah1, Bf[2][1], acc2);
            acc3 = MFMA16H(ah1, Bf[3][1], acc3);
            acc0 = MFMA16H(ah2, Bf[0][2], acc0);
            acc1 = MFMA16H(ah2, Bf[1][2], acc1);
            acc2 = MFMA16H(ah2, Bf[2][2], acc2);
            acc3 = MFMA16H(ah2, Bf[3][2], acc3);
            acc0 = MFMA16H(ah3, Bf[0][3], acc0);
            acc1 = MFMA16H(ah3, Bf[1][3], acc1);
            acc2 = MFMA16H(ah3, Bf[2][3], acc2);
            acc3 = MFMA16H(ah3, Bf[3][3], acc3);
            acc0 = MFMA16H(ah4, Bf[0][4], acc0);
            acc1 = MFMA16H(ah4, Bf[1][4], acc1);
            acc2 = MFMA16H(ah4, Bf[2][4], acc2);
            acc3 = MFMA16H(ah4, Bf[3][4], acc3);

            // ---- logit reduction (DPP, VALU pipe) overlaps MFMA latency ----
            if (t > 0 && w < RB) {
                float tot = wave_sum_dpp(dotp);
                if (l == 63) {
                    float beta = __expf(tot + attb);
                    Sreg += beta;
                    bcast[t & 1][w] = beta;
                }
            }

            // ---- activations: q=0 lanes own rows 0,1 of col jcol ----
            if (q == 0) {
#pragma unroll
                for (int r = 0; r < RB; ++r) {
                    float ig = fsig(acc0[r]);
                    float fg = fsig(acc1[r]);
                    float gg = ftanh(acc2[r]);
                    float og = fsig(acc3[r]);
                    c_st[r] = fmaf(fg, c_st[r], ig * gg);
                    float hv = og * ftanh(c_st[r]);
                    hpp[r]   = hprev[r];
                    hprev[r] = hv;
                    hs[t & 1][r][jcol] = (_Float16)hv;
                }
            }

            __syncthreads();   // single barrier per step
        }
    }

    // ---- epilogue ----
    // pending 1: beta_510 (bcast[1], written at t=511) applied to hpp=h_510
    {
        float2 bc = *(const float2*)&bcast[1][0];
        P[0] = fmaf(bc.x, hpp[0], P[0]);
        P[1] = fmaf(bc.y, hpp[1], P[1]);
    }
    // pending 2: logit for h_511 (buffer 1)
    if (w < RB) {
        half2v hh = *(const half2v*)&hs[1][w][2 * l];
        float dotp = fmaf(aw0, (float)hh[0], aw1 * (float)hh[1]);
        float tot = wave_sum_dpp(dotp);
        if (l == 63) {
            float beta = __expf(tot + attb);
            Sreg += beta;
            bcast[0][w] = beta;
            Sf[w] = Sreg;
        }
    }
    __syncthreads();
    // final P, scale by 1/S and fc weight, reduce across cols
    {
        float v0 = 0.f, v1 = 0.f;
        if (q == 0) {
            float2 bc = *(const float2*)&bcast[0][0];
            float Pv0 = fmaf(bc.x, hprev[0], P[0]);
            float Pv1 = fmaf(bc.y, hprev[1], P[1]);
            v0 = Pv0 * __builtin_amdgcn_rcpf(Sf[0]) * fcwj;
            v1 = Pv1 * __builtin_amdgcn_rcpf(Sf[1]) * fcwj;
        }
        float s0 = row_sum_dpp(v0);
        float s1 = row_sum_dpp(v1);
        if (l == 15) { part[w][0] = s0; part[w][1] = s1; }
    }
    __syncthreads();
    if (tid < RB) {
        float a = 0.f;
#pragma unroll
        for (int i = 0; i < 8; ++i) a += part[i][tid];
        out[b0 + tid] = a + fc_b[0];
    }
}

// ---------------------------------------------------------------------------
extern "C" void kernel_launch(void* const* d_in, const int* in_sizes, int n_in,
                              void* d_out, int out_size, void* d_ws, size_t ws_size,
                              hipStream_t stream) {
    const float* x      = (const float*)d_in[0];
    const float* w_ih   = (const float*)d_in[1];
    const float* u_ih   = (const float*)d_in[2];
    const float* w_hh   = (const float*)d_in[3];
    const float* u_hh   = (const float*)d_in[4];
    const float* b_ih   = (const float*)d_in[5];
    const float* b_hh   = (const float*)d_in[6];
    const float* attn_w = (const float*)d_in[7];
    const float* attn_b = (const float*)d_in[8];
    const float* fc_w   = (const float*)d_in[9];
    const float* u_fc   = (const float*)d_in[10];
    const float* fc_b   = (const float*)d_in[11];
    float* ws  = (float*)d_ws;
    float* out = (float*)d_out;

    std_kernel<<<TT, 256, 0, stream>>>(x, ws);
    sigma_kernel<<<1, 512, 0, stream>>>(w_ih, u_ih, w_hh, u_hh, fc_w, u_fc, ws);
    lstm_mfma<<<BB / RB, 512, 0, stream>>>(x, w_ih, w_hh, b_ih, b_hh,
                                           attn_w, attn_b, fc_w, fc_b, ws, out);
}

// Round 10
// 517.668 us; speedup vs baseline: 1.3808x; 1.1474x over previous
//
#include <hip/hip_runtime.h>
#include <math.h>

#define TT 512
#define BB 512
#define CC 32
#define CIN 33
#define HH 128
#define EPSF 1e-12f
#define CH 16              // timesteps per x-chunk staged in LDS
#define NCH (TT / CH)
#define RB 2               // batch rows per block

typedef _Float16 half8 __attribute__((ext_vector_type(8)));
typedef _Float16 half4v __attribute__((ext_vector_type(4)));
typedef _Float16 half2v __attribute__((ext_vector_type(2)));
typedef float f32x4 __attribute__((ext_vector_type(4)));

#define MFMA16H(a, b, c) __builtin_amdgcn_mfma_f32_16x16x32_f16(a, b, c, 0, 0, 0)

__device__ __forceinline__ float fsig(float x) {
    return __builtin_amdgcn_rcpf(1.f + __expf(-x));
}
__device__ __forceinline__ float ftanh(float x) {
    return 1.f - 2.f * __builtin_amdgcn_rcpf(1.f + __expf(2.f * x));
}
// full-wave (64) sum via DPP; result valid on lane 63 ONLY.
__device__ __forceinline__ float wave_sum_dpp(float x) {
    x += __int_as_float(__builtin_amdgcn_update_dpp(0, __float_as_int(x), 0x111, 0xf, 0xf, true));
    x += __int_as_float(__builtin_amdgcn_update_dpp(0, __float_as_int(x), 0x112, 0xf, 0xf, true));
    x += __int_as_float(__builtin_amdgcn_update_dpp(0, __float_as_int(x), 0x114, 0xf, 0xf, true));
    x += __int_as_float(__builtin_amdgcn_update_dpp(0, __float_as_int(x), 0x118, 0xf, 0xf, true));
    x += __int_as_float(__builtin_amdgcn_update_dpp(0, __float_as_int(x), 0x142, 0xa, 0xf, true));
    x += __int_as_float(__builtin_amdgcn_update_dpp(0, __float_as_int(x), 0x143, 0xc, 0xf, true));
    return x;
}
// sum within each 16-lane row; result valid on lanes 15/31/47/63.
__device__ __forceinline__ float row_sum_dpp(float x) {
    x += __int_as_float(__builtin_amdgcn_update_dpp(0, __float_as_int(x), 0x111, 0xf, 0xf, true));
    x += __int_as_float(__builtin_amdgcn_update_dpp(0, __float_as_int(x), 0x112, 0xf, 0xf, true));
    x += __int_as_float(__builtin_amdgcn_update_dpp(0, __float_as_int(x), 0x114, 0xf, 0xf, true));
    x += __int_as_float(__builtin_amdgcn_update_dpp(0, __float_as_int(x), 0x118, 0xf, 0xf, true));
    return x;
}

// ---------------------------------------------------------------------------
// Kernel 1: s[t] = mean_c std_b(x[:,t,c], ddof=1)   -> ws[0..511]
// ---------------------------------------------------------------------------
__global__ void std_kernel(const float* __restrict__ x, float* __restrict__ ws) {
    const int t = blockIdx.x;
    const int c = threadIdx.x & 31;
    const int sl = threadIdx.x >> 5;
    float sum = 0.f, sq = 0.f;
    for (int k = 0; k < 64; ++k) {
        const int b = sl * 64 + k;
        float v = x[((size_t)b * TT + t) * CC + c];
        sum += v;
        sq  = fmaf(v, v, sq);
    }
    __shared__ float rs[8][32];
    __shared__ float rq[8][32];
    rs[sl][c] = sum; rq[sl][c] = sq;
    __syncthreads();
    if (threadIdx.x < 32) {
        float S = 0.f, Q = 0.f;
        for (int i = 0; i < 8; ++i) { S += rs[i][threadIdx.x]; Q += rq[i][threadIdx.x]; }
        float mean = S / 512.0f;
        float var  = (Q - 512.0f * mean * mean) / 511.0f;
        rs[0][threadIdx.x] = sqrtf(fmaxf(var, 0.f));
    }
    __syncthreads();
    if (threadIdx.x == 0) {
        float m = 0.f;
        for (int i = 0; i < 32; ++i) m += rs[0][i];
        ws[t] = m / 32.0f;
    }
}

// ---------------------------------------------------------------------------
// Kernel 2: sigmas -> ws[512]=sig_ih, ws[513]=sig_hh, ws[514]=sig_fc
// ---------------------------------------------------------------------------
__global__ void sigma_kernel(const float* __restrict__ w_ih, const float* __restrict__ u_ih,
                             const float* __restrict__ w_hh, const float* __restrict__ u_hh,
                             const float* __restrict__ fc_w, const float* __restrict__ u_fc,
                             float* __restrict__ ws) {
    const int tid = threadIdx.x;
    __shared__ float red[512];
    __shared__ float vv[128];

    {   // sigma_hh
        const int c = tid & 127, q = tid >> 7;
        float part = 0.f;
        for (int g = q * 128; g < q * 128 + 128; ++g)
            part = fmaf(w_hh[g * HH + c], u_hh[g], part);
        red[tid] = part;
        __syncthreads();
        if (tid < 128) vv[tid] = red[tid] + red[tid + 128] + red[tid + 256] + red[tid + 384];
        __syncthreads();
        red[tid] = (tid < 128) ? vv[tid] * vv[tid] : 0.f;
        __syncthreads();
        for (int s = 64; s >= 1; s >>= 1) { if (tid < s) red[tid] += red[tid + s]; __syncthreads(); }
        const float nv = sqrtf(red[0]);
        __syncthreads();
        if (tid < 128) vv[tid] = vv[tid] / (nv + EPSF);
        __syncthreads();
        float wv = 0.f;
        for (int c2 = 0; c2 < 128; ++c2) wv = fmaf(w_hh[tid * HH + c2], vv[c2], wv);
        red[tid] = wv * wv;
        __syncthreads();
        for (int s = 256; s >= 1; s >>= 1) { if (tid < s) red[tid] += red[tid + s]; __syncthreads(); }
        if (tid == 0) { float ns2 = red[0]; ws[513] = ns2 / (sqrtf(ns2) + EPSF); }
        __syncthreads();
    }
    {   // sigma_ih
        float part = 0.f;
        if (tid < CIN) {
            for (int g = 0; g < 512; ++g) part = fmaf(w_ih[g * CIN + tid], u_ih[g], part);
            red[tid] = part;
        }
        __syncthreads();
        if (tid == 0) {
            float n2 = 0.f;
            for (int i = 0; i < CIN; ++i) n2 += red[i] * red[i];
            red[400] = sqrtf(n2);
        }
        __syncthreads();
        const float nv = red[400];
        if (tid < CIN) vv[tid] = red[tid] / (nv + EPSF);
        __syncthreads();
        float wv = 0.f;
        for (int c2 = 0; c2 < CIN; ++c2) wv = fmaf(w_ih[tid * CIN + c2], vv[c2], wv);
        red[tid] = wv * wv;
        __syncthreads();
        for (int s = 256; s >= 1; s >>= 1) { if (tid < s) red[tid] += red[tid + s]; __syncthreads(); }
        if (tid == 0) { float ns2 = red[0]; ws[512] = ns2 / (sqrtf(ns2) + EPSF); }
        __syncthreads();
    }
    {   // sigma_fc
        red[tid] = (tid < 128) ? fc_w[tid] * fc_w[tid] : 0.f;
        __syncthreads();
        for (int s = 64; s >= 1; s >>= 1) { if (tid < s) red[tid] += red[tid + s]; __syncthreads(); }
        if (tid == 0) {
            float nw2 = red[0];
            float u0  = u_fc[0];
            float nv  = fabsf(u0) * sqrtf(nw2);
            float wv  = u0 * nw2 / (nv + EPSF);
            ws[514]   = wv * wv / (fabsf(wv) + EPSF);
        }
    }
}

// ---------------------------------------------------------------------------
// Kernel 3: fp16 MFMA LSTM. 256 blocks x 2 batch rows, 512 threads (8 waves).
// Round-10 VALU diet: (1) duplicate-row A-frags -- all 64 lanes read
// hs[m&1]/xs[m&1]; D-rows 2..15 are copies, and reg (q&1) of EVERY lane holds
// the gates for row q&1, so activations are full-wave with no data movement.
// (2) MFMA C starts from pinned zero4 (no splat movs); bias+w32*s folded into
// activation. (3) state (c,h,P) is one scalar per lane.
// ---------------------------------------------------------------------------
__global__ __attribute__((amdgpu_flat_work_group_size(512, 512), amdgpu_waves_per_eu(2, 2)))
void lstm_mfma(
    const float* __restrict__ x,
    const float* __restrict__ w_ih, const float* __restrict__ w_hh,
    const float* __restrict__ b_ih, const float* __restrict__ b_hh,
    const float* __restrict__ attn_w, const float* __restrict__ attn_b,
    const float* __restrict__ fc_w, const float* __restrict__ fc_b,
    const float* __restrict__ ws,
    float* __restrict__ out)
{
    const int tid = threadIdx.x;
    const int w   = tid >> 6;          // wave 0..7
    const int l   = tid & 63;          // lane
    const int m   = l & 15;            // A-row / B-col index
    const int q   = l >> 4;            // quad 0..3
    const int r   = q & 1;             // this lane's batch row (duplicated rows)
    const int b0  = blockIdx.x * RB;
    const int jcol = 16 * w + m;       // this lane's h column

    const float rih = 1.f / ws[512];
    const float rhh = 1.f / ws[513];
    const float rfc = 1.f / ws[514];
    const float attb = attn_b[0];

    __shared__ __align__(16) _Float16 hs[2][RB][136];       // h planes
    __shared__ __align__(16) _Float16 xs[2][CH][RB][48];    // x chunks
    __shared__ float ss[2][CH];
    __shared__ __align__(8) float bcast[2][RB];             // beta per row
    __shared__ float Sf[RB];
    __shared__ float part[8][RB];                           // FC partials

    // ---- stationary fp16 weights: Bf[p][kt] ----
    half8 Bf[4][5];
    float biasg[4], w32g[4];
#pragma unroll
    for (int p = 0; p < 4; ++p) {
        const int g = 16 * w + 128 * p + m;
#pragma unroll
        for (int kt = 0; kt < 4; ++kt) {
            const float* src = w_hh + (size_t)g * HH + kt * 32 + q * 8;
#pragma unroll
            for (int i = 0; i < 8; ++i) Bf[p][kt][i] = (_Float16)(src[i] * rhh);
        }
        {
            const float* src = w_ih + (size_t)g * CIN + q * 8;
#pragma unroll
            for (int i = 0; i < 8; ++i) Bf[p][4][i] = (_Float16)(src[i] * rih);
        }
        w32g[p]  = w_ih[(size_t)g * CIN + 32] * rih;
        biasg[p] = b_ih[g] + b_hh[g];
    }
    f32x4 zero4 = (f32x4){0.f, 0.f, 0.f, 0.f};
#pragma unroll
    for (int p = 0; p < 4; ++p) {
#pragma unroll
        for (int kt = 0; kt < 5; ++kt) asm volatile("" : "+v"(Bf[p][kt]));
        asm volatile("" : "+v"(biasg[p]), "+v"(w32g[p]));
    }
    asm volatile("" : "+v"(zero4));
    const float fcwj = fc_w[jcol] * rfc;

    // logit-phase constants (waves 0..1 handle batch rows 0..1, lane = 2 cols)
    const float aw0 = attn_w[2 * l];
    const float aw1 = attn_w[2 * l + 1];

    // zero h_{-1} planes (both buffers)
    for (int i = tid; i < 2 * RB * 136; i += 512) (&hs[0][0][0])[i] = (_Float16)0.f;
    // stage chunk 0 + ss[0]
    if (tid < 256) {
        const int c4 = tid & 7, rr = (tid >> 3) & 1, k = tid >> 4;
        float4 xv = *reinterpret_cast<const float4*>(x + ((size_t)(b0 + rr) * TT + k) * CC + c4 * 4);
        half4v hv = {(_Float16)xv.x, (_Float16)xv.y, (_Float16)xv.z, (_Float16)xv.w};
        *(half4v*)&xs[0][k][rr][c4 * 4] = hv;
    }
    if (tid < CH) ss[0][tid] = ws[tid];

    float c_st = 0.f, P = 0.f, hprev = 0.f, hpp = 0.f;  // per-lane, row r
    float Sreg = 0.f;                                    // lane 63 of waves 0,1
    __syncthreads();

    for (int tc = 0; tc < NCH; ++tc) {
        const int cb = tc & 1;

        // stage next chunk
        if (tc + 1 < NCH) {
            const int nb  = (tc + 1) & 1;
            const int t0n = (tc + 1) * CH;
            if (tid < 256) {
                const int c4 = tid & 7, rr = (tid >> 3) & 1, k = tid >> 4;
                float4 xv = *reinterpret_cast<const float4*>(
                    x + ((size_t)(b0 + rr) * TT + (t0n + k)) * CC + c4 * 4);
                half4v hv = {(_Float16)xv.x, (_Float16)xv.y, (_Float16)xv.z, (_Float16)xv.w};
                *(half4v*)&xs[nb][k][rr][c4 * 4] = hv;
            }
            if (tid < CH) ss[nb][tid] = ws[t0n + tid];
        }

        for (int k = 0; k < CH; ++k) {
            const int t  = tc * CH + k;
            const int hb = (t + 1) & 1;    // buffer holding h_{t-1}

            // ---- A-frags: all lanes read duplicated rows (m&1) ----
            half8 ah0 = *(const half8*)&hs[hb][m & 1][0 * 32 + q * 8];
            half8 ah1 = *(const half8*)&hs[hb][m & 1][1 * 32 + q * 8];
            half8 ah2 = *(const half8*)&hs[hb][m & 1][2 * 32 + q * 8];
            half8 ah3 = *(const half8*)&hs[hb][m & 1][3 * 32 + q * 8];
            half8 ah4 = *(const half8*)&xs[cb][k][m & 1][q * 8];
            const float s_t = ss[cb][k];

            // logit source read issued early (h_{t-1}, buffer hb)
            float dotp = 0.f;
            if (t > 0 && w < RB) {
                half2v hh = *(const half2v*)&hs[hb][w][2 * l];
                dotp = fmaf(aw0, (float)hh[0], aw1 * (float)hh[1]);
            }

            // ---- P update for h_{t-2} (beta written at step t-1) ----
            if (t >= 2) P = fmaf(bcast[(t - 1) & 1][r], hpp, P);

            // ---- gates: 20 MFMA from zero C, 4 interleaved chains ----
            f32x4 acc0 = MFMA16H(ah0, Bf[0][0], zero4);
            f32x4 acc1 = MFMA16H(ah0, Bf[1][0], zero4);
            f32x4 acc2 = MFMA16H(ah0, Bf[2][0], zero4);
            f32x4 acc3 = MFMA16H(ah0, Bf[3][0], zero4);
            acc0 = MFMA16H(ah1, Bf[0][1], acc0);
            acc1 = MFMA16H(ah1, Bf[1][1], acc1);
            acc2 = MFMA16H(ah1, Bf[2][1], acc2);
            acc3 = MFMA16H(ah1, Bf[3][1], acc3);
            acc0 = MFMA16H(ah2, Bf[0][2], acc0);
            acc1 = MFMA16H(ah2, Bf[1][2], acc1);
            acc2 = MFMA16H(ah2, Bf[2][2], acc2);
            acc3 = MFMA16H(ah2, Bf[3][2], acc3);
            acc0 = MFMA16H(ah3, Bf[0][3], acc0);
            acc1 = MFMA16H(ah3, Bf[1][3], acc1);
            acc2 = MFMA16H(ah3, Bf[2][3], acc2);
            acc3 = MFMA16H(ah3, Bf[3][3], acc3);
            acc0 = MFMA16H(ah4, Bf[0][4], acc0);
            acc1 = MFMA16H(ah4, Bf[1][4], acc1);
            acc2 = MFMA16H(ah4, Bf[2][4], acc2);
            acc3 = MFMA16H(ah4, Bf[3][4], acc3);

            // ---- logit reduction (DPP) overlaps MFMA latency ----
            if (t > 0 && w < RB) {
                float tot = wave_sum_dpp(dotp);
                if (l == 63) {
                    float beta = __expf(tot + attb);
                    Sreg += beta;
                    bcast[t & 1][w] = beta;
                }
            }

            // ---- activations: full wave, reg r = this lane's row ----
            {
                float g0 = acc0[r] + fmaf(w32g[0], s_t, biasg[0]);
                float g1 = acc1[r] + fmaf(w32g[1], s_t, biasg[1]);
                float g2 = acc2[r] + fmaf(w32g[2], s_t, biasg[2]);
                float g3 = acc3[r] + fmaf(w32g[3], s_t, biasg[3]);
                float ig = fsig(g0);
                float fg = fsig(g1);
                float gg = ftanh(g2);
                float og = fsig(g3);
                c_st = fmaf(fg, c_st, ig * gg);
                float hv = og * ftanh(c_st);
                hpp   = hprev;
                hprev = hv;
                if (q < 2) hs[t & 1][r][jcol] = (_Float16)hv;
            }

            __syncthreads();   // single barrier per step
        }
    }

    // ---- epilogue ----
    // pending 1: beta_510 (bcast[1], written at t=511) applied to hpp=h_510
    P = fmaf(bcast[1][r], hpp, P);
    // pending 2: logit for h_511 (buffer 1)
    if (w < RB) {
        half2v hh = *(const half2v*)&hs[1][w][2 * l];
        float dotp = fmaf(aw0, (float)hh[0], aw1 * (float)hh[1]);
        float tot = wave_sum_dpp(dotp);
        if (l == 63) {
            float beta = __expf(tot + attb);
            Sreg += beta;
            bcast[0][w] = beta;
            Sf[w] = Sreg;
        }
    }
    __syncthreads();
    // final P, scale, per-row reduce (rows of 16 lanes are independent in DPP)
    {
        float Pv = fmaf(bcast[0][r], hprev, P);
        float v  = Pv * __builtin_amdgcn_rcpf(Sf[r]) * fcwj;
        float rs = row_sum_dpp(v);
        if (l == 15) part[w][0] = rs;       // row 0 sum (q=0)
        if (l == 31) part[w][1] = rs;       // row 1 sum (q=1)
    }
    __syncthreads();
    if (tid < RB) {
        float a = 0.f;
#pragma unroll
        for (int i = 0; i < 8; ++i) a += part[i][tid];
        out[b0 + tid] = a + fc_b[0];
    }
}

// ---------------------------------------------------------------------------
extern "C" void kernel_launch(void* const* d_in, const int* in_sizes, int n_in,
                              void* d_out, int out_size, void* d_ws, size_t ws_size,
                              hipStream_t stream) {
    const float* x      = (const float*)d_in[0];
    const float* w_ih   = (const float*)d_in[1];
    const float* u_ih   = (const float*)d_in[2];
    const float* w_hh   = (const float*)d_in[3];
    const float* u_hh   = (const float*)d_in[4];
    const float* b_ih   = (const float*)d_in[5];
    const float* b_hh   = (const float*)d_in[6];
    const float* attn_w = (const float*)d_in[7];
    const float* attn_b = (const float*)d_in[8];
    const float* fc_w   = (const float*)d_in[9];
    const float* u_fc   = (const float*)d_in[10];
    const float* fc_b   = (const float*)d_in[11];
    float* ws  = (float*)d_ws;
    float* out = (float*)d_out;

    std_kernel<<<TT, 256, 0, stream>>>(x, ws);
    sigma_kernel<<<1, 512, 0, stream>>>(w_ih, u_ih, w_hh, u_hh, fc_w, u_fc, ws);
    lstm_mfma<<<BB / RB, 512, 0, stream>>>(x, w_ih, w_hh, b_ih, b_hh,
                                           attn_w, attn_b, fc_w, fc_b, ws, out);
}

// Round 11
// 513.839 us; speedup vs baseline: 1.3911x; 1.0075x over previous
//
#include <hip/hip_runtime.h>
#include <math.h>

#define TT 512
#define BB 512
#define CC 32
#define CIN 33
#define HH 128
#define EPSF 1e-12f
#define CH 16              // timesteps per x-chunk staged in LDS
#define NCH (TT / CH)
#define RB 2               // batch rows per block
#define HSP 160            // hs row stride (halves): 320 B == 16 banks -> rows disjoint
#define XSP 96             // xs row stride (halves): 192 B == 16 banks

typedef _Float16 half8 __attribute__((ext_vector_type(8)));
typedef _Float16 half4v __attribute__((ext_vector_type(4)));
typedef _Float16 half2v __attribute__((ext_vector_type(2)));
typedef float f32x4 __attribute__((ext_vector_type(4)));

#define MFMA16H(a, b, c) __builtin_amdgcn_mfma_f32_16x16x32_f16(a, b, c, 0, 0, 0)

__device__ __forceinline__ float fsig(float x) {
    return __builtin_amdgcn_rcpf(1.f + __expf(-x));
}
__device__ __forceinline__ float ftanh(float x) {
    return 1.f - 2.f * __builtin_amdgcn_rcpf(1.f + __expf(2.f * x));
}
// full-wave (64) sum via DPP; result valid on lane 63 ONLY.
__device__ __forceinline__ float wave_sum_dpp(float x) {
    x += __int_as_float(__builtin_amdgcn_update_dpp(0, __float_as_int(x), 0x111, 0xf, 0xf, true));
    x += __int_as_float(__builtin_amdgcn_update_dpp(0, __float_as_int(x), 0x112, 0xf, 0xf, true));
    x += __int_as_float(__builtin_amdgcn_update_dpp(0, __float_as_int(x), 0x114, 0xf, 0xf, true));
    x += __int_as_float(__builtin_amdgcn_update_dpp(0, __float_as_int(x), 0x118, 0xf, 0xf, true));
    x += __int_as_float(__builtin_amdgcn_update_dpp(0, __float_as_int(x), 0x142, 0xa, 0xf, true));
    x += __int_as_float(__builtin_amdgcn_update_dpp(0, __float_as_int(x), 0x143, 0xc, 0xf, true));
    return x;
}
// sum within each 16-lane row; result valid on lanes 15/31/47/63.
__device__ __forceinline__ float row_sum_dpp(float x) {
    x += __int_as_float(__builtin_amdgcn_update_dpp(0, __float_as_int(x), 0x111, 0xf, 0xf, true));
    x += __int_as_float(__builtin_amdgcn_update_dpp(0, __float_as_int(x), 0x112, 0xf, 0xf, true));
    x += __int_as_float(__builtin_amdgcn_update_dpp(0, __float_as_int(x), 0x114, 0xf, 0xf, true));
    x += __int_as_float(__builtin_amdgcn_update_dpp(0, __float_as_int(x), 0x118, 0xf, 0xf, true));
    return x;
}

// ---------------------------------------------------------------------------
// Kernel 1 (fused prep): blocks 0..511 -> std feature s[t]; block 512 -> sigmas.
// ws[0..511]=s[t], ws[512]=sig_ih, ws[513]=sig_hh, ws[514]=sig_fc
// ---------------------------------------------------------------------------
__global__ __launch_bounds__(512) void prep_kernel(
    const float* __restrict__ x,
    const float* __restrict__ w_ih, const float* __restrict__ u_ih,
    const float* __restrict__ w_hh, const float* __restrict__ u_hh,
    const float* __restrict__ fc_w, const float* __restrict__ u_fc,
    float* __restrict__ ws)
{
    const int tid = threadIdx.x;
    __shared__ float rs[16][32];
    __shared__ float rq[16][32];
    __shared__ float red[512];
    __shared__ float vv[128];

    if (blockIdx.x < TT) {
        // ---- std over batch for timestep t ----
        const int t = blockIdx.x;
        const int c = tid & 31;
        const int sl = tid >> 5;               // 16 slices of 32 batch rows
        float sum = 0.f, sq = 0.f;
        for (int k = 0; k < 32; ++k) {
            const int b = sl * 32 + k;
            float v = x[((size_t)b * TT + t) * CC + c];
            sum += v;
            sq  = fmaf(v, v, sq);
        }
        rs[sl][c] = sum; rq[sl][c] = sq;
        __syncthreads();
        if (tid < 32) {
            float S = 0.f, Q = 0.f;
            for (int i = 0; i < 16; ++i) { S += rs[i][tid]; Q += rq[i][tid]; }
            float mean = S / 512.0f;
            float var  = (Q - 512.0f * mean * mean) / 511.0f;
            rs[0][tid] = sqrtf(fmaxf(var, 0.f));
        }
        __syncthreads();
        if (tid == 0) {
            float m = 0.f;
            for (int i = 0; i < 32; ++i) m += rs[0][i];
            ws[t] = m / 32.0f;
        }
        return;
    }

    // ---- sigmas (single block) ----
    const int wv_ = tid >> 6;
    const int l   = tid & 63;

    {   // sigma_hh : W [512,128]
        const int c = tid & 127, q = tid >> 7;
        float part = 0.f;
        for (int g = q * 128; g < q * 128 + 128; ++g)
            part = fmaf(w_hh[g * HH + c], u_hh[g], part);
        red[tid] = part;
        __syncthreads();
        if (tid < 128) vv[tid] = red[tid] + red[tid + 128] + red[tid + 256] + red[tid + 384];
        __syncthreads();
        red[tid] = (tid < 128) ? vv[tid] * vv[tid] : 0.f;
        __syncthreads();
        for (int s = 64; s >= 1; s >>= 1) { if (tid < s) red[tid] += red[tid + s]; __syncthreads(); }
        const float nv = sqrtf(red[0]);
        __syncthreads();
        if (tid < 128) vv[tid] = vv[tid] / (nv + EPSF);
        __syncthreads();
        // W @ v: wave-per-row, coalesced float2, DPP reduce
        float sq = 0.f;
        for (int gi = 0; gi < 64; ++gi) {
            const int g = wv_ * 64 + gi;
            float2 wl = *reinterpret_cast<const float2*>(&w_hh[(size_t)g * HH + 2 * l]);
            float2 vl = *reinterpret_cast<const float2*>(&vv[2 * l]);
            float p  = fmaf(wl.x, vl.x, wl.y * vl.y);
            float tot = wave_sum_dpp(p);
            sq = fmaf(tot, tot, sq);
        }
        if (l == 63) red[wv_] = sq;
        __syncthreads();
        if (tid == 0) {
            float ns2 = 0.f;
            for (int i = 0; i < 8; ++i) ns2 += red[i];
            ws[513] = ns2 / (sqrtf(ns2) + EPSF);
        }
        __syncthreads();
    }
    {   // sigma_ih : W [512,33]
        float part = 0.f;
        if (tid < CIN) {
            for (int g = 0; g < 512; ++g) part = fmaf(w_ih[g * CIN + tid], u_ih[g], part);
            red[tid] = part;
        }
        __syncthreads();
        if (tid == 0) {
            float n2 = 0.f;
            for (int i = 0; i < CIN; ++i) n2 += red[i] * red[i];
            red[400] = sqrtf(n2);
        }
        __syncthreads();
        const float nv = red[400];
        if (tid < CIN) vv[tid] = red[tid] / (nv + EPSF);
        __syncthreads();
        // W @ v: wave-per-row, DPP reduce (lanes >= CIN contribute 0)
        float vl = (l < CIN) ? vv[l] : 0.f;
        float sq = 0.f;
        for (int gi = 0; gi < 64; ++gi) {
            const int g = wv_ * 64 + gi;
            float p = (l < CIN) ? w_ih[(size_t)g * CIN + l] * vl : 0.f;
            float tot = wave_sum_dpp(p);
            sq = fmaf(tot, tot, sq);
        }
        if (l == 63) red[wv_] = sq;
        __syncthreads();
        if (tid == 0) {
            float ns2 = 0.f;
            for (int i = 0; i < 8; ++i) ns2 += red[i];
            ws[512] = ns2 / (sqrtf(ns2) + EPSF);
        }
        __syncthreads();
    }
    {   // sigma_fc : W [1,128]
        red[tid] = (tid < 128) ? fc_w[tid] * fc_w[tid] : 0.f;
        __syncthreads();
        for (int s = 64; s >= 1; s >>= 1) { if (tid < s) red[tid] += red[tid + s]; __syncthreads(); }
        if (tid == 0) {
            float nw2 = red[0];
            float u0  = u_fc[0];
            float nv  = fabsf(u0) * sqrtf(nw2);
            float wv  = u0 * nw2 / (nv + EPSF);
            ws[514]   = wv * wv / (fabsf(wv) + EPSF);
        }
    }
}

// ---------------------------------------------------------------------------
// Kernel 2: fp16 MFMA LSTM. 256 blocks x 2 batch rows, 512 threads (8 waves).
// R10 structure + R11 bank-exact padding: hs stride 160 halves (320 B == 16
// banks -> row0 banks 0-15, row1 banks 16-31, disjoint in every b128), xs
// stride 96 halves (192 B == 16 banks). R10's 136/48 strides overlapped rows
// and cost 17.9M conflict-cycles per dispatch.
// ---------------------------------------------------------------------------
__global__ __attribute__((amdgpu_flat_work_group_size(512, 512), amdgpu_waves_per_eu(2, 2)))
void lstm_mfma(
    const float* __restrict__ x,
    const float* __restrict__ w_ih, const float* __restrict__ w_hh,
    const float* __restrict__ b_ih, const float* __restrict__ b_hh,
    const float* __restrict__ attn_w, const float* __restrict__ attn_b,
    const float* __restrict__ fc_w, const float* __restrict__ fc_b,
    const float* __restrict__ ws,
    float* __restrict__ out)
{
    const int tid = threadIdx.x;
    const int w   = tid >> 6;          // wave 0..7
    const int l   = tid & 63;          // lane
    const int m   = l & 15;            // A-row / B-col index
    const int q   = l >> 4;            // quad 0..3
    const int r   = q & 1;             // this lane's batch row (duplicated rows)
    const int b0  = blockIdx.x * RB;
    const int jcol = 16 * w + m;       // this lane's h column

    const float rih = 1.f / ws[512];
    const float rhh = 1.f / ws[513];
    const float rfc = 1.f / ws[514];
    const float attb = attn_b[0];

    __shared__ __align__(16) _Float16 hs[2][RB][HSP];       // h planes
    __shared__ __align__(16) _Float16 xs[2][CH][RB][XSP];   // x chunks
    __shared__ float ss[2][CH];
    __shared__ __align__(8) float bcast[2][RB];             // beta per row
    __shared__ float Sf[RB];
    __shared__ float part[8][RB];                           // FC partials

    // ---- stationary fp16 weights: Bf[p][kt] ----
    half8 Bf[4][5];
    float biasg[4], w32g[4];
#pragma unroll
    for (int p = 0; p < 4; ++p) {
        const int g = 16 * w + 128 * p + m;
#pragma unroll
        for (int kt = 0; kt < 4; ++kt) {
            const float* src = w_hh + (size_t)g * HH + kt * 32 + q * 8;
#pragma unroll
            for (int i = 0; i < 8; ++i) Bf[p][kt][i] = (_Float16)(src[i] * rhh);
        }
        {
            const float* src = w_ih + (size_t)g * CIN + q * 8;
#pragma unroll
            for (int i = 0; i < 8; ++i) Bf[p][4][i] = (_Float16)(src[i] * rih);
        }
        w32g[p]  = w_ih[(size_t)g * CIN + 32] * rih;
        biasg[p] = b_ih[g] + b_hh[g];
    }
    f32x4 zero4 = (f32x4){0.f, 0.f, 0.f, 0.f};
#pragma unroll
    for (int p = 0; p < 4; ++p) {
#pragma unroll
        for (int kt = 0; kt < 5; ++kt) asm volatile("" : "+v"(Bf[p][kt]));
        asm volatile("" : "+v"(biasg[p]), "+v"(w32g[p]));
    }
    asm volatile("" : "+v"(zero4));
    const float fcwj = fc_w[jcol] * rfc;

    // logit-phase constants (waves 0..1 handle batch rows 0..1, lane = 2 cols)
    const float aw0 = attn_w[2 * l];
    const float aw1 = attn_w[2 * l + 1];

    // zero h_{-1} planes (both buffers)
    for (int i = tid; i < 2 * RB * HSP; i += 512) (&hs[0][0][0])[i] = (_Float16)0.f;
    // stage chunk 0 + ss[0]
    if (tid < 256) {
        const int c4 = tid & 7, rr = (tid >> 3) & 1, k = tid >> 4;
        float4 xv = *reinterpret_cast<const float4*>(x + ((size_t)(b0 + rr) * TT + k) * CC + c4 * 4);
        half4v hv = {(_Float16)xv.x, (_Float16)xv.y, (_Float16)xv.z, (_Float16)xv.w};
        *(half4v*)&xs[0][k][rr][c4 * 4] = hv;
    }
    if (tid < CH) ss[0][tid] = ws[tid];

    float c_st = 0.f, P = 0.f, hprev = 0.f, hpp = 0.f;  // per-lane, row r
    float Sreg = 0.f;                                    // lane 63 of waves 0,1
    __syncthreads();

    for (int tc = 0; tc < NCH; ++tc) {
        const int cb = tc & 1;

        // stage next chunk
        if (tc + 1 < NCH) {
            const int nb  = (tc + 1) & 1;
            const int t0n = (tc + 1) * CH;
            if (tid < 256) {
                const int c4 = tid & 7, rr = (tid >> 3) & 1, k = tid >> 4;
                float4 xv = *reinterpret_cast<const float4*>(
                    x + ((size_t)(b0 + rr) * TT + (t0n + k)) * CC + c4 * 4);
                half4v hv = {(_Float16)xv.x, (_Float16)xv.y, (_Float16)xv.z, (_Float16)xv.w};
                *(half4v*)&xs[nb][k][rr][c4 * 4] = hv;
            }
            if (tid < CH) ss[nb][tid] = ws[t0n + tid];
        }

        for (int k = 0; k < CH; ++k) {
            const int t  = tc * CH + k;
            const int hb = (t + 1) & 1;    // buffer holding h_{t-1}

            // ---- A-frags: all lanes read duplicated rows (m&1) ----
            half8 ah0 = *(const half8*)&hs[hb][m & 1][0 * 32 + q * 8];
            half8 ah1 = *(const half8*)&hs[hb][m & 1][1 * 32 + q * 8];
            half8 ah2 = *(const half8*)&hs[hb][m & 1][2 * 32 + q * 8];
            half8 ah3 = *(const half8*)&hs[hb][m & 1][3 * 32 + q * 8];
            half8 ah4 = *(const half8*)&xs[cb][k][m & 1][q * 8];
            const float s_t = ss[cb][k];

            // logit source read issued early (h_{t-1}, buffer hb)
            float dotp = 0.f;
            if (t > 0 && w < RB) {
                half2v hh = *(const half2v*)&hs[hb][w][2 * l];
                dotp = fmaf(aw0, (float)hh[0], aw1 * (float)hh[1]);
            }

            // ---- P update for h_{t-2} (beta written at step t-1) ----
            if (t >= 2) P = fmaf(bcast[(t - 1) & 1][r], hpp, P);

            // ---- gates: 20 MFMA from zero C, 4 interleaved chains ----
            f32x4 acc0 = MFMA16H(ah0, Bf[0][0], zero4);
            f32x4 acc1 = MFMA16H(ah0, Bf[1][0], zero4);
            f32x4 acc2 = MFMA16H(ah0, Bf[2][0], zero4);
            f32x4 acc3 = MFMA16H(ah0, Bf[3][0], zero4);
            acc0 = MFMA16H(ah1, Bf[0][1], acc0);
            acc1 = MFMA16H(ah1, Bf[1][1], acc1);
            acc2 = MFMA16H(ah1, Bf[2][1], acc2);
            acc3 = MFMA16H(ah1, Bf[3][1], acc3);
            acc0 = MFMA16H(ah2, Bf[0][2], acc0);
            acc1 = MFMA16H(ah2, Bf[1][2], acc1);
            acc2 = MFMA16H(ah2, Bf[2][2], acc2);
            acc3 = MFMA16H(ah2, Bf[3][2], acc3);
            acc0 = MFMA16H(ah3, Bf[0][3], acc0);
            acc1 = MFMA16H(ah3, Bf[1][3], acc1);
            acc2 = MFMA16H(ah3, Bf[2][3], acc2);
            acc3 = MFMA16H(ah3, Bf[3][3], acc3);
            acc0 = MFMA16H(ah4, Bf[0][4], acc0);
            acc1 = MFMA16H(ah4, Bf[1][4], acc1);
            acc2 = MFMA16H(ah4, Bf[2][4], acc2);
            acc3 = MFMA16H(ah4, Bf[3][4], acc3);

            // ---- logit reduction (DPP) overlaps MFMA latency ----
            if (t > 0 && w < RB) {
                float tot = wave_sum_dpp(dotp);
                if (l == 63) {
                    float beta = __expf(tot + attb);
                    Sreg += beta;
                    bcast[t & 1][w] = beta;
                }
            }

            // ---- activations: full wave, reg r = this lane's row ----
            {
                float g0 = acc0[r] + fmaf(w32g[0], s_t, biasg[0]);
                float g1 = acc1[r] + fmaf(w32g[1], s_t, biasg[1]);
                float g2 = acc2[r] + fmaf(w32g[2], s_t, biasg[2]);
                float g3 = acc3[r] + fmaf(w32g[3], s_t, biasg[3]);
                float ig = fsig(g0);
                float fg = fsig(g1);
                float gg = ftanh(g2);
                float og = fsig(g3);
                c_st = fmaf(fg, c_st, ig * gg);
                float hv = og * ftanh(c_st);
                hpp   = hprev;
                hprev = hv;
                if (q < 2) hs[t & 1][r][jcol] = (_Float16)hv;
            }

            __syncthreads();   // single barrier per step
        }
    }

    // ---- epilogue ----
    // pending 1: beta_510 (bcast[1], written at t=511) applied to hpp=h_510
    P = fmaf(bcast[1][r], hpp, P);
    // pending 2: logit for h_511 (buffer 1)
    if (w < RB) {
        half2v hh = *(const half2v*)&hs[1][w][2 * l];
        float dotp = fmaf(aw0, (float)hh[0], aw1 * (float)hh[1]);
        float tot = wave_sum_dpp(dotp);
        if (l == 63) {
            float beta = __expf(tot + attb);
            Sreg += beta;
            bcast[0][w] = beta;
            Sf[w] = Sreg;
        }
    }
    __syncthreads();
    // final P, scale, per-row reduce (16-lane rows independent in DPP)
    {
        float Pv = fmaf(bcast[0][r], hprev, P);
        float v  = Pv * __builtin_amdgcn_rcpf(Sf[r]) * fcwj;
        float rs = row_sum_dpp(v);
        if (l == 15) part[w][0] = rs;       // row 0 sum (q=0)
        if (l == 31) part[w][1] = rs;       // row 1 sum (q=1)
    }
    __syncthreads();
    if (tid < RB) {
        float a = 0.f;
#pragma unroll
        for (int i = 0; i < 8; ++i) a += part[i][tid];
        out[b0 + tid] = a + fc_b[0];
    }
}

// ---------------------------------------------------------------------------
extern "C" void kernel_launch(void* const* d_in, const int* in_sizes, int n_in,
                              void* d_out, int out_size, void* d_ws, size_t ws_size,
                              hipStream_t stream) {
    const float* x      = (const float*)d_in[0];
    const float* w_ih   = (const float*)d_in[1];
    const float* u_ih   = (const float*)d_in[2];
    const float* w_hh   = (const float*)d_in[3];
    const float* u_hh   = (const float*)d_in[4];
    const float* b_ih   = (const float*)d_in[5];
    const float* b_hh   = (const float*)d_in[6];
    const float* attn_w = (const float*)d_in[7];
    const float* attn_b = (const float*)d_in[8];
    const float* fc_w   = (const float*)d_in[9];
    const float* u_fc   = (const float*)d_in[10];
    const float* fc_b   = (const float*)d_in[11];
    float* ws  = (float*)d_ws;
    float* out = (float*)d_out;

    prep_kernel<<<TT + 1, 512, 0, stream>>>(x, w_ih, u_ih, w_hh, u_hh, fc_w, u_fc, ws);
    lstm_mfma<<<BB / RB, 512, 0, stream>>>(x, w_ih, w_hh, b_ih, b_hh,
                                           attn_w, attn_b, fc_w, fc_b, ws, out);
}